// Round 2
// baseline (38139.468 us; speedup 1.0000x reference)
//
#include <hip/hip_runtime.h>
#include <math.h>

#define N_NODES 10000
#define N_EDGES 100000
#define NB      64
#define EMB     100
#define H       2000
#define LAYERS  4

#define C1_OC 50
#define C1_L  666
#define C2_OC 100
#define C2_L  221
#define C3_OC 150
#define C3_L  73
#define LIN1_IN  10950
#define LIN1_OUT 500

// split-GEMM geometry
#define MP   10112        // N_NODES padded to 128
#define SEG  2016         // H padded to 32 (one split segment)
#define LDA  4032         // physical A/B row: [hi(2016) | lo(2016)] ushorts
#define KP   6048         // virtual K = 3 segments (hi*hi, hi*lo, lo*hi)
#define NPW  2048         // padded N for W_ggc gemm
#define NPG  6016         // padded N for gate gemms
#define BM 128
#define BN 128
#define BK 32

using short8 = __attribute__((ext_vector_type(8))) short;
using f32x4  = __attribute__((ext_vector_type(4))) float;

// ---- bf16 helpers (RNE) ----
__device__ inline unsigned short f2bf(float x) {
  unsigned u = __float_as_uint(x);
  unsigned r = (u + 0x7fffu + ((u >> 16) & 1u)) >> 16;
  return (unsigned short)r;
}
__device__ inline float bf2f(unsigned short u) {
  return __uint_as_float(((unsigned)u) << 16);
}

__device__ inline void gload16(const void* g, void* l) {
  __builtin_amdgcn_global_load_lds(
      (const __attribute__((address_space(1))) unsigned int*)g,
      (__attribute__((address_space(3))) unsigned int*)l, 16, 0, 0);
}

// ---------------- embedding: h fp32 + split ----------------
__global__ void embed_split_kernel(const int* __restrict__ tokens,
                                   const float* __restrict__ table,
                                   float* __restrict__ h, unsigned short* __restrict__ hh) {
  int n = blockIdx.x;
  int tok = tokens[n];
  for (int c = threadIdx.x; c < SEG; c += 256) {
    float v = (c < EMB) ? table[tok * EMB + c] : 0.f;
    if (c < H) h[(size_t)n * H + c] = v;
    unsigned short hi = f2bf(v);
    hh[(size_t)n * LDA + c] = hi;
    hh[(size_t)n * LDA + SEG + c] = f2bf(v - bf2f(hi));
  }
}

// ---------------- CSR build ----------------
__global__ void hist_kernel(const int* __restrict__ dst, int* __restrict__ counts, int e) {
  int i = blockIdx.x * 256 + threadIdx.x;
  if (i < e) atomicAdd(&counts[dst[i]], 1);
}

__global__ void scan_kernel(const int* __restrict__ counts, int* __restrict__ row_off, int n) {
  __shared__ int sums[1024];
  int tid = threadIdx.x;
  const int CH = (n + 1023) / 1024;
  int start = tid * CH;
  int local = 0;
  for (int i = 0; i < CH; i++)
    if (start + i < n) local += counts[start + i];
  sums[tid] = local;
  __syncthreads();
  for (int off = 1; off < 1024; off <<= 1) {
    int v = (tid >= off) ? sums[tid - off] : 0;
    __syncthreads();
    sums[tid] += v;
    __syncthreads();
  }
  int run = (tid > 0) ? sums[tid - 1] : 0;
  for (int i = 0; i < CH; i++)
    if (start + i < n) { row_off[start + i] = run; run += counts[start + i]; }
  if (tid == 1023) row_off[n] = run;
}

__global__ void scatter_kernel(const int* __restrict__ src, const int* __restrict__ dst,
                               const int* __restrict__ row_off, int* __restrict__ cursor,
                               int* __restrict__ csr_src, int e) {
  int i = blockIdx.x * 256 + threadIdx.x;
  if (i < e) {
    int d = dst[i];
    int pos = atomicAdd(&cursor[d], 1);
    csr_src[row_off[d] + pos] = src[i];
  }
}

__global__ void starts_kernel(const int* __restrict__ batch, int* __restrict__ starts, int n) {
  int i = blockIdx.x * 256 + threadIdx.x;
  if (i >= n) return;
  int b = batch[i];
  int pb = (i == 0) ? -1 : batch[i - 1];
  if (b != pb)
    for (int x = pb + 1; x <= b; x++) starts[x] = i;
  if (i == n - 1)
    for (int x = b + 1; x <= NB; x++) starts[x] = n;
}

// ---------------- weight prep: W (Nreal x H) -> Bt [hi|lo], Np x LDA ----------------
__global__ void prep_wbt_kernel(const float* __restrict__ W, unsigned short* __restrict__ out,
                                int Nreal) {
  int n = blockIdx.y;
  int k = blockIdx.x * 256 + threadIdx.x;
  if (k >= SEG) return;
  float v = (n < Nreal && k < H) ? W[(size_t)n * H + k] : 0.f;
  unsigned short hi = f2bf(v);
  out[(size_t)n * LDA + k] = hi;
  out[(size_t)n * LDA + SEG + k] = f2bf(v - bf2f(hi));
}

// W_ggc[l] (H x H), transpose+split -> out[l]: NPW x LDA
__global__ void prep_wg_kernel(const float* __restrict__ Wg, unsigned short* __restrict__ out) {
  __shared__ float t[32][33];
  int l = blockIdx.z;
  const float* W = Wg + (size_t)l * H * H;
  unsigned short* o = out + (size_t)l * NPW * LDA;
  int kt = blockIdx.x * 32, nt = blockIdx.y * 32;
  int tx = threadIdx.x & 31, ty = threadIdx.x >> 5;   // ty 0..7
#pragma unroll
  for (int i = 0; i < 4; i++) {
    int k = kt + ty + i * 8, n = nt + tx;
    float v = (k < H && n < H) ? W[(size_t)k * H + n] : 0.f;
    t[tx][ty + i * 8] = v;   // t[n_local][k_local]
  }
  __syncthreads();
#pragma unroll
  for (int i = 0; i < 4; i++) {
    int nl = ty + i * 8, kl = tx;
    int n = nt + nl, k = kt + kl;
    float v = t[nl][kl];
    unsigned short hi = f2bf(v);
    o[(size_t)n * LDA + k] = hi;
    o[(size_t)n * LDA + SEG + k] = f2bf(v - bf2f(hi));
  }
}

// ---------------- split GEMM: C[m][n] = sum_k A[m,:]·Bt[n,:] (3-product bf16) ----------------
__global__ __launch_bounds__(256) void gemm_split_kernel(
    const unsigned short* __restrict__ A, const unsigned short* __restrict__ Bt,
    float* __restrict__ C, int Nreal, int Mreal) {
  __shared__ __align__(16) unsigned short As[BM][BK];
  __shared__ __align__(16) unsigned short Bs[BN][BK];
  const int tid = threadIdx.x;
  const int wave = tid >> 6;
  const int lane = tid & 63;
  const int bm = blockIdx.y * BM;
  const int bn = blockIdx.x * BN;
  const int wm = (wave & 1) * 64;
  const int wn = (wave >> 1) * 64;
  const int srow = lane >> 2;          // 0..15
  const int scol = (lane & 3) * 8;     // 0,8,16,24
  const int fr = lane & 15;
  const int quad = lane >> 4;

  f32x4 acc[4][4];
#pragma unroll
  for (int i = 0; i < 4; i++)
#pragma unroll
    for (int j = 0; j < 4; j++) {
      f32x4 z = {0.f, 0.f, 0.f, 0.f};
      acc[i][j] = z;
    }

  for (int k0 = 0; k0 < KP; k0 += BK) {
    // virtual-K -> physical column remap:
    //  seg0: A hi, B hi ; seg1: A hi, B lo ; seg2: A lo, B hi
    int ka = (k0 < SEG) ? k0 : k0 - SEG;            // hi, hi, lo
    int kb = (k0 < 2 * SEG) ? k0 : k0 - 2 * SEG;    // hi, lo, hi
    gload16(A + (size_t)(bm + wave * 32 + srow) * LDA + ka + scol, &As[wave * 32][0]);
    gload16(A + (size_t)(bm + wave * 32 + 16 + srow) * LDA + ka + scol, &As[wave * 32 + 16][0]);
    gload16(Bt + (size_t)(bn + wave * 32 + srow) * LDA + kb + scol, &Bs[wave * 32][0]);
    gload16(Bt + (size_t)(bn + wave * 32 + 16 + srow) * LDA + kb + scol, &Bs[wave * 32 + 16][0]);
    __syncthreads();
    short8 af[4], bf[4];
#pragma unroll
    for (int i = 0; i < 4; i++) {
      af[i] = *(const short8*)&As[wm + i * 16 + fr][quad * 8];
      bf[i] = *(const short8*)&Bs[wn + i * 16 + fr][quad * 8];
    }
#pragma unroll
    for (int i = 0; i < 4; i++)
#pragma unroll
      for (int j = 0; j < 4; j++)
        acc[i][j] = __builtin_amdgcn_mfma_f32_16x16x32_bf16(af[i], bf[j], acc[i][j], 0, 0, 0);
    __syncthreads();
  }
#pragma unroll
  for (int i = 0; i < 4; i++) {
#pragma unroll
    for (int j = 0; j < 4; j++) {
      int n = bn + wn + j * 16 + fr;
      if (n >= Nreal) continue;
#pragma unroll
      for (int r = 0; r < 4; r++) {
        int mrow = bm + wm + i * 16 + quad * 4 + r;
        if (mrow < Mreal) C[(size_t)mrow * Nreal + n] = acc[i][j][r];
      }
    }
  }
}

// ---------------- edge aggregation, writes split directly ----------------
__device__ inline void write_split4(unsigned short* __restrict__ aggh, int node, int chunk,
                                    float4 a) {
  int c = chunk * 4;
  ushort4 hi, lo;
  hi.x = f2bf(a.x); lo.x = f2bf(a.x - bf2f(hi.x));
  hi.y = f2bf(a.y); lo.y = f2bf(a.y - bf2f(hi.y));
  hi.z = f2bf(a.z); lo.z = f2bf(a.z - bf2f(hi.z));
  hi.w = f2bf(a.w); lo.w = f2bf(a.w - bf2f(hi.w));
  *(ushort4*)&aggh[(size_t)node * LDA + c] = hi;
  *(ushort4*)&aggh[(size_t)node * LDA + SEG + c] = lo;
}

__global__ void agg_split_kernel(const float* __restrict__ msrc, const int* __restrict__ row_off,
                                 const int* __restrict__ csr_src,
                                 unsigned short* __restrict__ aggh) {
  int node = blockIdx.x;
  int s = row_off[node], e = row_off[node + 1];
  int tid = threadIdx.x;
  const float4* m4 = (const float4*)msrc;
  float4 a0 = make_float4(0, 0, 0, 0), a1 = make_float4(0, 0, 0, 0);
  int c0 = tid, c1 = tid + 256;
  __shared__ int s_src[256];
  for (int base = s; base < e; base += 256) {
    int cnt = min(256, e - base);
    __syncthreads();
    if (tid < cnt) s_src[tid] = csr_src[base + tid];
    __syncthreads();
    for (int p = 0; p < cnt; p++) {
      const float4* row = m4 + (size_t)s_src[p] * (H / 4);
      float4 v = row[c0];
      a0.x += v.x; a0.y += v.y; a0.z += v.z; a0.w += v.w;
      if (c1 < H / 4) {
        float4 w = row[c1];
        a1.x += w.x; a1.y += w.y; a1.z += w.z; a1.w += w.w;
      }
    }
  }
  write_split4(aggh, node, c0, a0);
  if (c1 < SEG / 4)
    write_split4(aggh, node, c1, (c1 < H / 4) ? a1 : make_float4(0, 0, 0, 0));
}

// ---------------- GRU elementwise epilogue (in-place h) ----------------
__global__ void gru_elem_kernel(const float* __restrict__ gi, const float* __restrict__ gh,
                                const float* __restrict__ b_ih, const float* __restrict__ b_hh,
                                float* __restrict__ h, unsigned short* __restrict__ hh) {
  int m = blockIdx.y;
  int chunk = blockIdx.x * 256 + threadIdx.x;
  if (chunk >= SEG / 4) return;
  int c = chunk * 4;
  if (c >= H) {
    ushort4 z; z.x = z.y = z.z = z.w = 0;
    *(ushort4*)&hh[(size_t)m * LDA + c] = z;
    *(ushort4*)&hh[(size_t)m * LDA + SEG + c] = z;
    return;
  }
  const float4 gir = *(const float4*)&gi[(size_t)m * (3 * H) + c];
  const float4 giz = *(const float4*)&gi[(size_t)m * (3 * H) + H + c];
  const float4 gin = *(const float4*)&gi[(size_t)m * (3 * H) + 2 * H + c];
  const float4 ghr = *(const float4*)&gh[(size_t)m * (3 * H) + c];
  const float4 ghz = *(const float4*)&gh[(size_t)m * (3 * H) + H + c];
  const float4 ghn = *(const float4*)&gh[(size_t)m * (3 * H) + 2 * H + c];
  const float4 bir = *(const float4*)&b_ih[c];
  const float4 biz = *(const float4*)&b_ih[H + c];
  const float4 bin = *(const float4*)&b_ih[2 * H + c];
  const float4 bhr = *(const float4*)&b_hh[c];
  const float4 bhz = *(const float4*)&b_hh[H + c];
  const float4 bhn = *(const float4*)&b_hh[2 * H + c];
  float4 hv = *(const float4*)&h[(size_t)m * H + c];
  float out[4];
  float girA[4] = {gir.x, gir.y, gir.z, gir.w};
  float gizA[4] = {giz.x, giz.y, giz.z, giz.w};
  float ginA[4] = {gin.x, gin.y, gin.z, gin.w};
  float ghrA[4] = {ghr.x, ghr.y, ghr.z, ghr.w};
  float ghzA[4] = {ghz.x, ghz.y, ghz.z, ghz.w};
  float ghnA[4] = {ghn.x, ghn.y, ghn.z, ghn.w};
  float birA[4] = {bir.x, bir.y, bir.z, bir.w};
  float bizA[4] = {biz.x, biz.y, biz.z, biz.w};
  float binA[4] = {bin.x, bin.y, bin.z, bin.w};
  float bhrA[4] = {bhr.x, bhr.y, bhr.z, bhr.w};
  float bhzA[4] = {bhz.x, bhz.y, bhz.z, bhz.w};
  float bhnA[4] = {bhn.x, bhn.y, bhn.z, bhn.w};
  float hvA[4] = {hv.x, hv.y, hv.z, hv.w};
#pragma unroll
  for (int i = 0; i < 4; i++) {
    float r = 1.f / (1.f + expf(-((girA[i] + birA[i]) + (ghrA[i] + bhrA[i]))));
    float z = 1.f / (1.f + expf(-((gizA[i] + bizA[i]) + (ghzA[i] + bhzA[i]))));
    float nn = tanhf((ginA[i] + binA[i]) + r * (ghnA[i] + bhnA[i]));
    out[i] = (1.f - z) * nn + z * hvA[i];
  }
  float4 ov = make_float4(out[0], out[1], out[2], out[3]);
  *(float4*)&h[(size_t)m * H + c] = ov;
  write_split4(hh, m, chunk, ov);
}

// ---------------- tail: pool / convs / linears ----------------
__global__ void pool_kernel(const float* __restrict__ h, const int* __restrict__ starts,
                            float* __restrict__ pooled) {
  int b = blockIdx.x;
  int s = starts[b], e = starts[b + 1];
  const float4* h4 = (const float4*)h;
  float4* p4 = (float4*)pooled;
  for (int idx = threadIdx.x; idx < H / 4; idx += 256) {
    float4 mx = make_float4(-1e30f, -1e30f, -1e30f, -1e30f);
    for (int n = s; n < e; n++) {
      float4 v = h4[(size_t)n * (H / 4) + idx];
      mx.x = fmaxf(mx.x, v.x); mx.y = fmaxf(mx.y, v.y);
      mx.z = fmaxf(mx.z, v.z); mx.w = fmaxf(mx.w, v.w);
    }
    mx.x = fmaxf(mx.x, 0.f); mx.y = fmaxf(mx.y, 0.f);
    mx.z = fmaxf(mx.z, 0.f); mx.w = fmaxf(mx.w, 0.f);
    p4[b * (H / 4) + idx] = mx;
  }
}

__global__ void conv1_kernel(const float* __restrict__ in, const float* __restrict__ w,
                             const float* __restrict__ bias, float* __restrict__ outp) {
  __shared__ float sin_[H];
  int b = blockIdx.x;
  for (int j = threadIdx.x; j < H; j += 256) sin_[j] = in[(size_t)b * H + j];
  __syncthreads();
  for (int idx = threadIdx.x; idx < C1_OC * C1_L; idx += 256) {
    int oc = idx / C1_L, t = idx % C1_L;
    float w0 = w[oc * 3], w1 = w[oc * 3 + 1], w2 = w[oc * 3 + 2];
    float bb = bias[oc];
    float best = 0.f;
    int base = t * 3;
#pragma unroll
    for (int p = 0; p < 3; p++) {
      float v = fmaf(sin_[base + p], w0, fmaf(sin_[base + p + 1], w1,
                fmaf(sin_[base + p + 2], w2, bb)));
      best = fmaxf(best, v);
    }
    outp[((size_t)b * C1_OC + oc) * C1_L + t] = best;
  }
}

__global__ void conv2_kernel(const float* __restrict__ in, const float* __restrict__ w,
                             const float* __restrict__ bias, float* __restrict__ outp) {
  int idx = blockIdx.x * 256 + threadIdx.x;
  if (idx >= NB * C2_OC * C2_L) return;
  int t = idx % C2_L;
  int rem = idx / C2_L;
  int oc = rem % C2_OC;
  int b = rem / C2_OC;
  const float* ip = in + (size_t)b * C1_OC * C1_L;
  const float* wp = w + oc * C1_OC * 3;
  float bb = bias[oc];
  float s0 = bb, s1 = bb, s2 = bb;
  int tc = t * 3;
  for (int ic = 0; ic < C1_OC; ic++) {
    const float* r = ip + ic * C1_L + tc;
    float v0 = r[0], v1 = r[1], v2 = r[2], v3 = r[3], v4 = r[4];
    float w0 = wp[ic * 3], w1 = wp[ic * 3 + 1], w2 = wp[ic * 3 + 2];
    s0 = fmaf(v0, w0, fmaf(v1, w1, fmaf(v2, w2, s0)));
    s1 = fmaf(v1, w0, fmaf(v2, w1, fmaf(v3, w2, s1)));
    s2 = fmaf(v2, w0, fmaf(v3, w1, fmaf(v4, w2, s2)));
  }
  outp[idx] = fmaxf(fmaxf(s0, fmaxf(s1, s2)), 0.f);
}

__global__ void conv3_kernel(const float* __restrict__ in, const float* __restrict__ w,
                             const float* __restrict__ bias, float* __restrict__ outp) {
  int idx = blockIdx.x * 256 + threadIdx.x;
  if (idx >= NB * C3_OC * C3_L) return;
  int t = idx % C3_L;
  int rem = idx / C3_L;
  int oc = rem % C3_OC;
  int b = rem / C3_OC;
  const float* ip = in + (size_t)b * C2_OC * C2_L;
  const float* wp = w + oc * C2_OC * 3;
  float bb = bias[oc];
  float s0 = bb, s1 = bb, s2 = bb;
  int tc = t * 3;
  for (int ic = 0; ic < C2_OC; ic++) {
    const float* r = ip + ic * C2_L + tc;
    float v0 = r[0], v1 = r[1], v2 = r[2], v3 = r[3], v4 = r[4];
    float w0 = wp[ic * 3], w1 = wp[ic * 3 + 1], w2 = wp[ic * 3 + 2];
    s0 = fmaf(v0, w0, fmaf(v1, w1, fmaf(v2, w2, s0)));
    s1 = fmaf(v1, w0, fmaf(v2, w1, fmaf(v3, w2, s1)));
    s2 = fmaf(v2, w0, fmaf(v3, w1, fmaf(v4, w2, s2)));
  }
  outp[idx] = fmaxf(fmaxf(s0, fmaxf(s1, s2)), 0.f);
}

__global__ void lin1_kernel(const float* __restrict__ x, const float* __restrict__ w,
                            const float* __restrict__ bias, float* __restrict__ outp) {
  int gid = blockIdx.x * 4 + (threadIdx.x >> 6);
  int lane = threadIdx.x & 63;
  int b = gid / LIN1_OUT;
  int o = gid % LIN1_OUT;
  const float* xp = x + (size_t)b * LIN1_IN;
  const float* wp = w + (size_t)o * LIN1_IN;
  float s = 0.f;
  for (int k = lane; k < LIN1_IN; k += 64) s = fmaf(xp[k], wp[k], s);
#pragma unroll
  for (int off = 32; off > 0; off >>= 1) s += __shfl_down(s, off, 64);
  if (lane == 0) outp[b * LIN1_OUT + o] = fmaxf(s + bias[o], 0.f);
}

__global__ void lin2_kernel(const float* __restrict__ x, const float* __restrict__ w,
                            const float* __restrict__ bias, float* __restrict__ outp) {
  int tid = threadIdx.x;
  int b = tid >> 2, o = tid & 3;
  const float* xp = x + b * LIN1_OUT;
  const float* wp = w + o * LIN1_OUT;
  float s = bias[o];
  for (int k = 0; k < LIN1_OUT; k++) s = fmaf(xp[k], wp[k], s);
  outp[b * 4 + o] = fmaxf(s, 0.f);
}

// ================= fallback fp32 path (round-1, known-good) =================
__global__ void embed_kernel(const int* __restrict__ tokens, const float* __restrict__ table,
                             float* __restrict__ h) {
  int n = blockIdx.x;
  int tok = tokens[n];
  for (int j = threadIdx.x; j < H; j += 256)
    h[(size_t)n * H + j] = (j < EMB) ? table[tok * EMB + j] : 0.f;
}

__global__ __launch_bounds__(256) void gemm_nn_kernel(
    const float* __restrict__ A, const float* __restrict__ B, float* __restrict__ C,
    int M, int N, int K) {
  __shared__ float As[16][64];
  __shared__ float Bs[16][64];
  const int tid = threadIdx.x;
  const int bm = blockIdx.y * 64;
  const int bn = blockIdx.x * 64;
  const int tx = tid & 15;
  const int ty = tid >> 4;
  const int arow = tid >> 2;
  const int acol = (tid & 3) * 4;
  const int brow = tid >> 4;
  const int bcol = (tid & 15) * 4;
  float acc[4][4] = {};
  for (int k0 = 0; k0 < K; k0 += 16) {
    float4 av = make_float4(0.f, 0.f, 0.f, 0.f);
    if (bm + arow < M)
      av = *(const float4*)(A + (size_t)(bm + arow) * K + (k0 + acol));
    As[acol + 0][arow] = av.x;
    As[acol + 1][arow] = av.y;
    As[acol + 2][arow] = av.z;
    As[acol + 3][arow] = av.w;
    float4 bv = make_float4(0.f, 0.f, 0.f, 0.f);
    if (bn + bcol < N)
      bv = *(const float4*)(B + (size_t)(k0 + brow) * N + (bn + bcol));
    *(float4*)&Bs[brow][bcol] = bv;
    __syncthreads();
#pragma unroll
    for (int kk = 0; kk < 16; kk++) {
      float4 a = *(const float4*)&As[kk][ty * 4];
      float4 b = *(const float4*)&Bs[kk][tx * 4];
      float ar[4] = {a.x, a.y, a.z, a.w};
      float br[4] = {b.x, b.y, b.z, b.w};
#pragma unroll
      for (int i = 0; i < 4; i++)
#pragma unroll
        for (int j = 0; j < 4; j++)
          acc[i][j] = fmaf(ar[i], br[j], acc[i][j]);
    }
    __syncthreads();
  }
#pragma unroll
  for (int i = 0; i < 4; i++) {
    int row = bm + ty * 4 + i;
    if (row < M && bn + tx * 4 < N) {
      float4 v = make_float4(acc[i][0], acc[i][1], acc[i][2], acc[i][3]);
      *(float4*)(C + (size_t)row * N + bn + tx * 4) = v;
    }
  }
}

__global__ void agg_kernel(const float* __restrict__ m, const int* __restrict__ row_off,
                           const int* __restrict__ csr_src, float* __restrict__ agg) {
  int n = blockIdx.x;
  int s = row_off[n], e = row_off[n + 1];
  int tid = threadIdx.x;
  const float4* m4 = (const float4*)m;
  float4* a4 = (float4*)agg;
  float4 acc0 = make_float4(0, 0, 0, 0), acc1 = make_float4(0, 0, 0, 0);
  int idx0 = tid, idx1 = tid + 256;
  __shared__ int s_src[256];
  for (int base = s; base < e; base += 256) {
    int cnt = min(256, e - base);
    __syncthreads();
    if (tid < cnt) s_src[tid] = csr_src[base + tid];
    __syncthreads();
    for (int p = 0; p < cnt; p++) {
      size_t roff = (size_t)s_src[p] * (H / 4);
      float4 v0 = m4[roff + idx0];
      acc0.x += v0.x; acc0.y += v0.y; acc0.z += v0.z; acc0.w += v0.w;
      if (idx1 < H / 4) {
        float4 v1 = m4[roff + idx1];
        acc1.x += v1.x; acc1.y += v1.y; acc1.z += v1.z; acc1.w += v1.w;
      }
    }
  }
  a4[(size_t)n * (H / 4) + idx0] = acc0;
  if (idx1 < H / 4) a4[(size_t)n * (H / 4) + idx1] = acc1;
}

__global__ __launch_bounds__(256) void gru_fused_kernel(
    const float* __restrict__ agg, const float* __restrict__ hcur,
    const float* __restrict__ W_ih, const float* __restrict__ W_hh,
    const float* __restrict__ b_ih, const float* __restrict__ b_hh,
    float* __restrict__ hnew, int M) {
  __shared__ float Aa[16][64];
  __shared__ float Ah[16][64];
  __shared__ float Bs[6][16][32];
  const int tid = threadIdx.x;
  const int bm = blockIdx.y * 64;
  const int bn = blockIdx.x * 32;
  const int tx = tid & 15;
  const int ty = tid >> 4;
  const int arow = tid >> 2;
  const int acol = (tid & 3) * 4;
  float acc[6][4][2] = {};
  for (int k0 = 0; k0 < H; k0 += 16) {
    {
      float4 av = make_float4(0, 0, 0, 0), hv = make_float4(0, 0, 0, 0);
      if (bm + arow < M) {
        av = *(const float4*)(agg + (size_t)(bm + arow) * H + k0 + acol);
        hv = *(const float4*)(hcur + (size_t)(bm + arow) * H + k0 + acol);
      }
      Aa[acol + 0][arow] = av.x; Aa[acol + 1][arow] = av.y;
      Aa[acol + 2][arow] = av.z; Aa[acol + 3][arow] = av.w;
      Ah[acol + 0][arow] = hv.x; Ah[acol + 1][arow] = hv.y;
      Ah[acol + 2][arow] = hv.z; Ah[acol + 3][arow] = hv.w;
    }
#pragma unroll
    for (int t = 0; t < 3; t++) {
      int idx = tid + t * 256;
      int g = idx >> 7;
      int rem = idx & 127;
      int c = rem >> 2;
      int kq = (rem & 3) * 4;
      const float* W = (g < 3) ? W_ih : W_hh;
      int grow = (g % 3) * H + bn + c;
      float4 wv = make_float4(0, 0, 0, 0);
      if (bn + c < H)
        wv = *(const float4*)(W + (size_t)grow * H + k0 + kq);
      Bs[g][kq + 0][c] = wv.x; Bs[g][kq + 1][c] = wv.y;
      Bs[g][kq + 2][c] = wv.z; Bs[g][kq + 3][c] = wv.w;
    }
    __syncthreads();
#pragma unroll
    for (int kk = 0; kk < 16; kk++) {
      float4 a4 = *(const float4*)&Aa[kk][ty * 4];
      float4 h4 = *(const float4*)&Ah[kk][ty * 4];
      float aa[4] = {a4.x, a4.y, a4.z, a4.w};
      float hh[4] = {h4.x, h4.y, h4.z, h4.w};
      float bb[6][2];
#pragma unroll
      for (int g = 0; g < 6; g++) {
        float2 b2 = *(const float2*)&Bs[g][kk][tx * 2];
        bb[g][0] = b2.x; bb[g][1] = b2.y;
      }
#pragma unroll
      for (int i = 0; i < 4; i++)
#pragma unroll
        for (int j = 0; j < 2; j++) {
          acc[0][i][j] = fmaf(aa[i], bb[0][j], acc[0][i][j]);
          acc[1][i][j] = fmaf(aa[i], bb[1][j], acc[1][i][j]);
          acc[2][i][j] = fmaf(aa[i], bb[2][j], acc[2][i][j]);
          acc[3][i][j] = fmaf(hh[i], bb[3][j], acc[3][i][j]);
          acc[4][i][j] = fmaf(hh[i], bb[4][j], acc[4][i][j]);
          acc[5][i][j] = fmaf(hh[i], bb[5][j], acc[5][i][j]);
        }
    }
    __syncthreads();
  }
#pragma unroll
  for (int i = 0; i < 4; i++) {
    int row = bm + ty * 4 + i;
    if (row >= M) continue;
#pragma unroll
    for (int j = 0; j < 2; j++) {
      int cc = bn + tx * 2 + j;
      if (cc >= H) continue;
      float ir = acc[0][i][j] + b_ih[cc];
      float iz = acc[1][i][j] + b_ih[H + cc];
      float inn = acc[2][i][j] + b_ih[2 * H + cc];
      float hr = acc[3][i][j] + b_hh[cc];
      float hz = acc[4][i][j] + b_hh[H + cc];
      float hn = acc[5][i][j] + b_hh[2 * H + cc];
      float r = 1.f / (1.f + expf(-(ir + hr)));
      float z = 1.f / (1.f + expf(-(iz + hz)));
      float nn = tanhf(inn + r * hn);
      float hold = hcur[(size_t)row * H + cc];
      hnew[(size_t)row * H + cc] = (1.f - z) * nn + z * hold;
    }
  }
}

// ================= launch =================
extern "C" void kernel_launch(void* const* d_in, const int* in_sizes, int n_in,
                              void* d_out, int out_size, void* d_ws, size_t ws_size,
                              hipStream_t stream) {
  const int* tokens = (const int*)d_in[0];
  const int* edge_index = (const int*)d_in[1];
  const int* batch = (const int*)d_in[2];
  const float* embed = (const float*)d_in[3];
  const float* W_ggc = (const float*)d_in[4];
  const float* W_ih = (const float*)d_in[5];
  const float* W_hh = (const float*)d_in[6];
  const float* b_ih = (const float*)d_in[7];
  const float* b_hh = (const float*)d_in[8];
  const float* c1w = (const float*)d_in[9];
  const float* c1b = (const float*)d_in[10];
  const float* c2w = (const float*)d_in[11];
  const float* c2b = (const float*)d_in[12];
  const float* c3w = (const float*)d_in[13];
  const float* c3b = (const float*)d_in[14];
  const float* l1w = (const float*)d_in[15];
  const float* l1b = (const float*)d_in[16];
  const float* l2w = (const float*)d_in[17];
  const float* l2b = (const float*)d_in[18];
  float* out = (float*)d_out;

  const int* e_src = edge_index;
  const int* e_dst = edge_index + N_EDGES;

  char* ws = (char*)d_ws;
  size_t off = 0;
  auto alloc = [&](size_t bytes) -> void* {
    void* p = ws + off;
    off = (off + bytes + 255) & ~(size_t)255;
    return p;
  };

  const size_t NEED = (size_t)950 * 1024 * 1024;
  if (ws_size >= NEED) {
    // ---------- split-bf16 MFMA path ----------
    float* gi = (float*)alloc(sizeof(float) * (size_t)N_NODES * 3 * H);   // 240 MB
    float* m_f32 = gi;                                                    // alias (dead before gi)
    float* gh = (float*)alloc(sizeof(float) * (size_t)N_NODES * 3 * H);   // 240 MB
    float* h_f32 = (float*)alloc(sizeof(float) * (size_t)N_NODES * H);    // 80 MB
    unsigned short* h_half = (unsigned short*)alloc(sizeof(short) * (size_t)MP * LDA);
    unsigned short* agg_half = (unsigned short*)alloc(sizeof(short) * (size_t)MP * LDA);
    unsigned short* Wg_b = (unsigned short*)alloc(sizeof(short) * (size_t)LAYERS * NPW * LDA);
    unsigned short* Wih_b = (unsigned short*)alloc(sizeof(short) * (size_t)NPG * LDA);
    unsigned short* Whh_b = (unsigned short*)alloc(sizeof(short) * (size_t)NPG * LDA);
    float* pooled = (float*)alloc(sizeof(float) * NB * H);
    float* c1 = (float*)alloc(sizeof(float) * (size_t)NB * C1_OC * C1_L);
    float* c2 = (float*)alloc(sizeof(float) * (size_t)NB * C2_OC * C2_L);
    float* c3 = (float*)alloc(sizeof(float) * (size_t)NB * C3_OC * C3_L);
    float* l1out = (float*)alloc(sizeof(float) * NB * LIN1_OUT);
    int* counts = (int*)alloc(sizeof(int) * (N_NODES + 1));
    int* row_off = (int*)alloc(sizeof(int) * (N_NODES + 1));
    int* cursor = (int*)alloc(sizeof(int) * N_NODES);
    int* csr_src = (int*)alloc(sizeof(int) * N_EDGES);
    int* starts = (int*)alloc(sizeof(int) * (NB + 1));

    hipMemsetAsync(counts, 0, sizeof(int) * (N_NODES + 1), stream);
    hipMemsetAsync(cursor, 0, sizeof(int) * N_NODES, stream);
    // zero pad rows (rows N_NODES..MP) of split A-buffers
    hipMemsetAsync(h_half + (size_t)N_NODES * LDA, 0,
                   sizeof(short) * (size_t)(MP - N_NODES) * LDA, stream);
    hipMemsetAsync(agg_half + (size_t)N_NODES * LDA, 0,
                   sizeof(short) * (size_t)(MP - N_NODES) * LDA, stream);

    // weight prep
    {
      dim3 g((SEG + 255) / 256, NPG);
      prep_wbt_kernel<<<g, 256, 0, stream>>>(W_ih, Wih_b, 3 * H);
      prep_wbt_kernel<<<g, 256, 0, stream>>>(W_hh, Whh_b, 3 * H);
      dim3 gg(SEG / 32, NPW / 32, LAYERS);
      prep_wg_kernel<<<gg, 256, 0, stream>>>(W_ggc, Wg_b);
    }

    embed_split_kernel<<<N_NODES, 256, 0, stream>>>(tokens, embed, h_f32, h_half);
    hist_kernel<<<(N_EDGES + 255) / 256, 256, 0, stream>>>(e_dst, counts, N_EDGES);
    scan_kernel<<<1, 1024, 0, stream>>>(counts, row_off, N_NODES);
    scatter_kernel<<<(N_EDGES + 255) / 256, 256, 0, stream>>>(e_src, e_dst, row_off, cursor,
                                                              csr_src, N_EDGES);
    starts_kernel<<<(N_NODES + 255) / 256, 256, 0, stream>>>(batch, starts, N_NODES);

    dim3 grid_ggc(NPW / BN, MP / BM);
    dim3 grid_gate(NPG / BN, MP / BM);
    dim3 grid_gru(2, N_NODES);
    for (int l = 0; l < LAYERS; l++) {
      gemm_split_kernel<<<grid_ggc, 256, 0, stream>>>(
          h_half, Wg_b + (size_t)l * NPW * LDA, m_f32, H, N_NODES);
      agg_split_kernel<<<N_NODES, 256, 0, stream>>>(m_f32, row_off, csr_src, agg_half);
      gemm_split_kernel<<<grid_gate, 256, 0, stream>>>(agg_half, Wih_b, gi, 3 * H, N_NODES);
      gemm_split_kernel<<<grid_gate, 256, 0, stream>>>(h_half, Whh_b, gh, 3 * H, N_NODES);
      gru_elem_kernel<<<grid_gru, 256, 0, stream>>>(gi, gh, b_ih, b_hh, h_f32, h_half);
    }

    pool_kernel<<<NB, 256, 0, stream>>>(h_f32, starts, pooled);
    conv1_kernel<<<NB, 256, 0, stream>>>(pooled, c1w, c1b, c1);
    conv2_kernel<<<(NB * C2_OC * C2_L + 255) / 256, 256, 0, stream>>>(c1, c2w, c2b, c2);
    conv3_kernel<<<(NB * C3_OC * C3_L + 255) / 256, 256, 0, stream>>>(c2, c3w, c3b, c3);
    lin1_kernel<<<NB * LIN1_OUT / 4, 256, 0, stream>>>(c3, l1w, l1b, l1out);
    lin2_kernel<<<1, 256, 0, stream>>>(l1out, l2w, l2b, out);
  } else {
    // ---------- fallback fp32 path ----------
    float* buf0 = (float*)alloc(sizeof(float) * (size_t)N_NODES * H);
    float* buf1 = (float*)alloc(sizeof(float) * (size_t)N_NODES * H);
    float* buf2 = (float*)alloc(sizeof(float) * (size_t)N_NODES * H);
    float* pooled = (float*)alloc(sizeof(float) * NB * H);
    float* c1 = (float*)alloc(sizeof(float) * (size_t)NB * C1_OC * C1_L);
    float* c2 = (float*)alloc(sizeof(float) * (size_t)NB * C2_OC * C2_L);
    float* c3 = (float*)alloc(sizeof(float) * (size_t)NB * C3_OC * C3_L);
    float* l1out = (float*)alloc(sizeof(float) * NB * LIN1_OUT);
    int* counts = (int*)alloc(sizeof(int) * (N_NODES + 1));
    int* row_off = (int*)alloc(sizeof(int) * (N_NODES + 1));
    int* cursor = (int*)alloc(sizeof(int) * N_NODES);
    int* csr_src = (int*)alloc(sizeof(int) * N_EDGES);
    int* starts = (int*)alloc(sizeof(int) * (NB + 1));

    hipMemsetAsync(counts, 0, sizeof(int) * (N_NODES + 1), stream);
    hipMemsetAsync(cursor, 0, sizeof(int) * N_NODES, stream);

    embed_kernel<<<N_NODES, 256, 0, stream>>>(tokens, embed, buf0);
    hist_kernel<<<(N_EDGES + 255) / 256, 256, 0, stream>>>(e_dst, counts, N_EDGES);
    scan_kernel<<<1, 1024, 0, stream>>>(counts, row_off, N_NODES);
    scatter_kernel<<<(N_EDGES + 255) / 256, 256, 0, stream>>>(e_src, e_dst, row_off, cursor,
                                                              csr_src, N_EDGES);
    starts_kernel<<<(N_NODES + 255) / 256, 256, 0, stream>>>(batch, starts, N_NODES);

    float* h = buf0;
    float* s1 = buf1;
    float* s2 = buf2;
    dim3 gemm_grid((H + 63) / 64, (N_NODES + 63) / 64);
    dim3 gru_grid((H + 31) / 32, (N_NODES + 63) / 64);
    for (int l = 0; l < LAYERS; l++) {
      gemm_nn_kernel<<<gemm_grid, 256, 0, stream>>>(h, W_ggc + (size_t)l * H * H, s1,
                                                    N_NODES, H, H);
      agg_kernel<<<N_NODES, 256, 0, stream>>>(s1, row_off, csr_src, s2);
      gru_fused_kernel<<<gru_grid, 256, 0, stream>>>(s2, h, W_ih, W_hh, b_ih, b_hh, s1,
                                                     N_NODES);
      float* tmp = h; h = s1; s1 = tmp;
    }

    pool_kernel<<<NB, 256, 0, stream>>>(h, starts, pooled);
    conv1_kernel<<<NB, 256, 0, stream>>>(pooled, c1w, c1b, c1);
    conv2_kernel<<<(NB * C2_OC * C2_L + 255) / 256, 256, 0, stream>>>(c1, c2w, c2b, c2);
    conv3_kernel<<<(NB * C3_OC * C3_L + 255) / 256, 256, 0, stream>>>(c2, c3w, c3b, c3);
    lin1_kernel<<<NB * LIN1_OUT / 4, 256, 0, stream>>>(c3, l1w, l1b, l1out);
    lin2_kernel<<<1, 256, 0, stream>>>(l1out, l2w, l2b, out);
  }
}

// Round 3
// 5500.991 us; speedup vs baseline: 6.9332x; 6.9332x over previous
//
#include <hip/hip_runtime.h>
#include <math.h>

#define N_NODES 10000
#define N_EDGES 100000
#define NB      64
#define EMB     100
#define H       2000
#define LAYERS  4

#define C1_OC 50
#define C1_L  666
#define C2_OC 100
#define C2_L  221
#define C3_OC 150
#define C3_L  73
#define LIN1_IN  10950
#define LIN1_OUT 500

// fp16 GEMM geometry
#define SEG  2016          // K = H padded to 32
#define MP   10112         // M = N_NODES padded to 128
#define NW   2048          // Wg output cols padded to 128
#define NG   6048          // 3 * SEG (gate weight rows)

using half8 = __attribute__((ext_vector_type(8))) _Float16;
using f32x4 = __attribute__((ext_vector_type(4))) float;

__device__ inline void gload16(const void* g, void* l) {
  __builtin_amdgcn_global_load_lds(
      (const __attribute__((address_space(1))) unsigned int*)g,
      (__attribute__((address_space(3))) unsigned int*)l, 16, 0, 0);
}

// ---------------- embedding -> fp16 h ----------------
__global__ void embed16_kernel(const int* __restrict__ tokens,
                               const float* __restrict__ table,
                               _Float16* __restrict__ h) {
  int n = blockIdx.x;
  int tok = tokens[n];
  for (int c = threadIdx.x; c < SEG; c += 256) {
    float v = (c < EMB) ? table[tok * EMB + c] : 0.f;
    h[(size_t)n * SEG + c] = (_Float16)v;
  }
}

// ---------------- CSR build ----------------
__global__ void hist_kernel(const int* __restrict__ dst, int* __restrict__ counts, int e) {
  int i = blockIdx.x * 256 + threadIdx.x;
  if (i < e) atomicAdd(&counts[dst[i]], 1);
}

__global__ void scan_kernel(const int* __restrict__ counts, int* __restrict__ row_off, int n) {
  __shared__ int sums[1024];
  int tid = threadIdx.x;
  const int CH = (n + 1023) / 1024;
  int start = tid * CH;
  int local = 0;
  for (int i = 0; i < CH; i++)
    if (start + i < n) local += counts[start + i];
  sums[tid] = local;
  __syncthreads();
  for (int off = 1; off < 1024; off <<= 1) {
    int v = (tid >= off) ? sums[tid - off] : 0;
    __syncthreads();
    sums[tid] += v;
    __syncthreads();
  }
  int run = (tid > 0) ? sums[tid - 1] : 0;
  for (int i = 0; i < CH; i++)
    if (start + i < n) { row_off[start + i] = run; run += counts[start + i]; }
  if (tid == 1023) row_off[n] = run;
}

__global__ void scatter_kernel(const int* __restrict__ src, const int* __restrict__ dst,
                               const int* __restrict__ row_off, int* __restrict__ cursor,
                               int* __restrict__ csr_src, int e) {
  int i = blockIdx.x * 256 + threadIdx.x;
  if (i < e) {
    int d = dst[i];
    int pos = atomicAdd(&cursor[d], 1);
    csr_src[row_off[d] + pos] = src[i];
  }
}

__global__ void starts_kernel(const int* __restrict__ batch, int* __restrict__ starts, int n) {
  int i = blockIdx.x * 256 + threadIdx.x;
  if (i >= n) return;
  int b = batch[i];
  int pb = (i == 0) ? -1 : batch[i - 1];
  if (b != pb)
    for (int x = pb + 1; x <= b; x++) starts[x] = i;
  if (i == n - 1)
    for (int x = b + 1; x <= NB; x++) starts[x] = n;
}

// ---------------- weight prep ----------------
// W_ih/W_hh (3H x H) -> fp16 Bt rows: out[(g*SEG + c)][k]
__global__ void prep_wbt16_kernel(const float* __restrict__ W, _Float16* __restrict__ out) {
  int n = blockIdx.y;                       // 0..NG-1
  int k = blockIdx.x * 256 + threadIdx.x;
  if (k >= SEG) return;
  int g = n / SEG, c = n % SEG;
  float v = (c < H && k < H) ? W[(size_t)(g * H + c) * H + k] : 0.f;
  out[(size_t)n * SEG + k] = (_Float16)v;
}

// W_ggc[l] (H x H) -> transposed fp16 Bt: out[l][n][k] = W[k][n], n<NW, k<SEG
__global__ void prep_wg16_kernel(const float* __restrict__ Wg, _Float16* __restrict__ out) {
  __shared__ float t[32][33];
  int l = blockIdx.z;
  const float* W = Wg + (size_t)l * H * H;
  _Float16* o = out + (size_t)l * NW * SEG;
  int kt = blockIdx.x * 32, nt = blockIdx.y * 32;
  int tx = threadIdx.x & 31, ty = threadIdx.x >> 5;  // ty 0..7
#pragma unroll
  for (int i = 0; i < 4; i++) {
    int k = kt + ty + i * 8, n = nt + tx;
    t[tx][ty + i * 8] = (k < H && n < H) ? W[(size_t)k * H + n] : 0.f;
  }
  __syncthreads();
#pragma unroll
  for (int i = 0; i < 4; i++) {
    int nl = ty + i * 8, kl = tx;
    o[(size_t)(nt + nl) * SEG + (kt + kl)] = (_Float16)t[nl][kl];
  }
}

// ---------------- fp16 GEMM: C[m][n] = sum_k A[m][k] * Bt[n][k], fp16 out ----------------
__global__ __launch_bounds__(256) void gemm16_kernel(
    const _Float16* __restrict__ A, const _Float16* __restrict__ Bt,
    _Float16* __restrict__ C) {
  __shared__ __align__(16) _Float16 As[128][32];
  __shared__ __align__(16) _Float16 Bs[128][32];
  const int tid = threadIdx.x;
  const int wave = tid >> 6, lane = tid & 63;
  const int bm = blockIdx.y * 128, bn = blockIdx.x * 128;
  const int wm = (wave & 1) * 64, wn = (wave >> 1) * 64;
  const int srow = lane >> 2, scol = (lane & 3) * 8;
  const int fr = lane & 15, quad = lane >> 4;

  f32x4 acc[4][4];
#pragma unroll
  for (int i = 0; i < 4; i++)
#pragma unroll
    for (int j = 0; j < 4; j++) {
      f32x4 z = {0.f, 0.f, 0.f, 0.f};
      acc[i][j] = z;
    }

  for (int k0 = 0; k0 < SEG; k0 += 32) {
    gload16(A + (size_t)(bm + wave * 32 + srow) * SEG + k0 + scol, &As[wave * 32][0]);
    gload16(A + (size_t)(bm + wave * 32 + 16 + srow) * SEG + k0 + scol, &As[wave * 32 + 16][0]);
    gload16(Bt + (size_t)(bn + wave * 32 + srow) * SEG + k0 + scol, &Bs[wave * 32][0]);
    gload16(Bt + (size_t)(bn + wave * 32 + 16 + srow) * SEG + k0 + scol, &Bs[wave * 32 + 16][0]);
    __syncthreads();
    half8 af[4], bf[4];
#pragma unroll
    for (int i = 0; i < 4; i++) {
      af[i] = *(const half8*)&As[wm + i * 16 + fr][quad * 8];
      bf[i] = *(const half8*)&Bs[wn + i * 16 + fr][quad * 8];
    }
#pragma unroll
    for (int i = 0; i < 4; i++)
#pragma unroll
      for (int j = 0; j < 4; j++)
        acc[i][j] = __builtin_amdgcn_mfma_f32_16x16x32_f16(af[i], bf[j], acc[i][j], 0, 0, 0);
    __syncthreads();
  }
#pragma unroll
  for (int i = 0; i < 4; i++)
#pragma unroll
    for (int j = 0; j < 4; j++) {
      int n = bn + wn + j * 16 + fr;
      if (n >= SEG) continue;
#pragma unroll
      for (int r = 0; r < 4; r++) {
        int m = bm + wm + i * 16 + quad * 4 + r;
        C[(size_t)m * SEG + n] = (_Float16)acc[i][j][r];
      }
    }
}

// ---------------- edge aggregation on fp16 m, fp32 accumulate, fp16 out ----------------
__global__ void agg16_kernel(const _Float16* __restrict__ m, const int* __restrict__ row_off,
                             const int* __restrict__ csr_src, _Float16* __restrict__ agg) {
  int node = blockIdx.x;
  int s = row_off[node], e = row_off[node + 1];
  int tid = threadIdx.x;
  bool act = tid < (SEG / 8);   // 252
  float a[8] = {0, 0, 0, 0, 0, 0, 0, 0};
  __shared__ int s_src[256];
  for (int base = s; base < e; base += 256) {
    int cnt = min(256, e - base);
    __syncthreads();
    if (tid < cnt) s_src[tid] = csr_src[base + tid];
    __syncthreads();
    for (int p = 0; p < cnt; p++) {
      if (act) {
        half8 v = *(const half8*)&m[(size_t)s_src[p] * SEG + tid * 8];
#pragma unroll
        for (int i = 0; i < 8; i++) a[i] += (float)v[i];
      }
    }
  }
  if (act) {
    half8 o;
#pragma unroll
    for (int i = 0; i < 8; i++) o[i] = (_Float16)a[i];
    *(half8*)&agg[(size_t)node * SEG + tid * 8] = o;
  }
}

// ---------------- fused GRU: 6 gate GEMM tiles + elementwise epilogue ----------------
__global__ __launch_bounds__(256) void gru16_kernel(
    const _Float16* __restrict__ Agg, const _Float16* __restrict__ Hc,
    const _Float16* __restrict__ Wih, const _Float16* __restrict__ Whh,
    const float* __restrict__ b_ih, const float* __restrict__ b_hh,
    _Float16* __restrict__ Hn) {
  __shared__ __align__(16) _Float16 Aa[128][32];
  __shared__ __align__(16) _Float16 Ah[128][32];
  __shared__ __align__(16) _Float16 Bs[6][32][32];
  const int tid = threadIdx.x;
  const int wave = tid >> 6, lane = tid & 63;
  const int bm = blockIdx.y * 128, bc = blockIdx.x * 32;
  const int srow = lane >> 2, scol = (lane & 3) * 8;
  const int fr = lane & 15, quad = lane >> 4;

  f32x4 acc[6][2][2];
#pragma unroll
  for (int g = 0; g < 6; g++)
#pragma unroll
    for (int i = 0; i < 2; i++)
#pragma unroll
      for (int j = 0; j < 2; j++) {
        f32x4 z = {0.f, 0.f, 0.f, 0.f};
        acc[g][i][j] = z;
      }

  for (int k0 = 0; k0 < SEG; k0 += 32) {
    gload16(Agg + (size_t)(bm + wave * 32 + srow) * SEG + k0 + scol, &Aa[wave * 32][0]);
    gload16(Agg + (size_t)(bm + wave * 32 + 16 + srow) * SEG + k0 + scol, &Aa[wave * 32 + 16][0]);
    gload16(Hc + (size_t)(bm + wave * 32 + srow) * SEG + k0 + scol, &Ah[wave * 32][0]);
    gload16(Hc + (size_t)(bm + wave * 32 + 16 + srow) * SEG + k0 + scol, &Ah[wave * 32 + 16][0]);
#pragma unroll
    for (int j = 0; j < 3; j++) {
      int idx = wave * 3 + j;          // 0..11
      int t = idx >> 1, hf = idx & 1;
      const _Float16* W = (t < 3) ? Wih : Whh;
      int tr = (t < 3) ? t : t - 3;
      gload16(W + (size_t)(tr * SEG + bc + hf * 16 + srow) * SEG + k0 + scol,
              &Bs[t][hf * 16][0]);
    }
    __syncthreads();
    half8 afA[2], afH[2], bf[6][2];
#pragma unroll
    for (int mi = 0; mi < 2; mi++) {
      afA[mi] = *(const half8*)&Aa[wave * 32 + mi * 16 + fr][quad * 8];
      afH[mi] = *(const half8*)&Ah[wave * 32 + mi * 16 + fr][quad * 8];
    }
#pragma unroll
    for (int g = 0; g < 6; g++)
#pragma unroll
      for (int nj = 0; nj < 2; nj++)
        bf[g][nj] = *(const half8*)&Bs[g][nj * 16 + fr][quad * 8];
#pragma unroll
    for (int g = 0; g < 6; g++)
#pragma unroll
      for (int mi = 0; mi < 2; mi++)
#pragma unroll
        for (int nj = 0; nj < 2; nj++)
          acc[g][mi][nj] = __builtin_amdgcn_mfma_f32_16x16x32_f16(
              (g < 3) ? afA[mi] : afH[mi], bf[g][nj], acc[g][mi][nj], 0, 0, 0);
    __syncthreads();
  }

#pragma unroll
  for (int mi = 0; mi < 2; mi++)
#pragma unroll
    for (int nj = 0; nj < 2; nj++) {
      int c = bc + nj * 16 + fr;
#pragma unroll
      for (int r = 0; r < 4; r++) {
        int m = bm + wave * 32 + mi * 16 + quad * 4 + r;
        if (m >= N_NODES) continue;
        if (c < H) {
          float gir = acc[0][mi][nj][r] + b_ih[c];
          float giz = acc[1][mi][nj][r] + b_ih[H + c];
          float gin = acc[2][mi][nj][r] + b_ih[2 * H + c];
          float ghr = acc[3][mi][nj][r] + b_hh[c];
          float ghz = acc[4][mi][nj][r] + b_hh[H + c];
          float ghn = acc[5][mi][nj][r] + b_hh[2 * H + c];
          float rg = 1.f / (1.f + expf(-(gir + ghr)));
          float zg = 1.f / (1.f + expf(-(giz + ghz)));
          float nn = tanhf(gin + rg * ghn);
          float hold = (float)Hc[(size_t)m * SEG + c];
          Hn[(size_t)m * SEG + c] = (_Float16)((1.f - zg) * nn + zg * hold);
        } else {
          Hn[(size_t)m * SEG + c] = (_Float16)0.f;
        }
      }
    }
}

// ---------------- relu + segment max pool (fp16 in, fp32 out) ----------------
__global__ void pool16_kernel(const _Float16* __restrict__ h, const int* __restrict__ starts,
                              float* __restrict__ pooled) {
  int b = blockIdx.x;
  int s = starts[b], e = starts[b + 1];
  for (int idx = threadIdx.x; idx < H; idx += 256) {
    float mx = 0.f;  // relu floor
    for (int n = s; n < e; n++) mx = fmaxf(mx, (float)h[(size_t)n * SEG + idx]);
    pooled[b * H + idx] = mx;
  }
}

// ---------------- conv / linear tail (fp32, unchanged) ----------------
__global__ void conv1_kernel(const float* __restrict__ in, const float* __restrict__ w,
                             const float* __restrict__ bias, float* __restrict__ outp) {
  __shared__ float sin_[H];
  int b = blockIdx.x;
  for (int j = threadIdx.x; j < H; j += 256) sin_[j] = in[(size_t)b * H + j];
  __syncthreads();
  for (int idx = threadIdx.x; idx < C1_OC * C1_L; idx += 256) {
    int oc = idx / C1_L, t = idx % C1_L;
    float w0 = w[oc * 3], w1 = w[oc * 3 + 1], w2 = w[oc * 3 + 2];
    float bb = bias[oc];
    float best = 0.f;
    int base = t * 3;
#pragma unroll
    for (int p = 0; p < 3; p++) {
      float v = fmaf(sin_[base + p], w0, fmaf(sin_[base + p + 1], w1,
                fmaf(sin_[base + p + 2], w2, bb)));
      best = fmaxf(best, v);
    }
    outp[((size_t)b * C1_OC + oc) * C1_L + t] = best;
  }
}

__global__ void conv2_kernel(const float* __restrict__ in, const float* __restrict__ w,
                             const float* __restrict__ bias, float* __restrict__ outp) {
  int idx = blockIdx.x * 256 + threadIdx.x;
  if (idx >= NB * C2_OC * C2_L) return;
  int t = idx % C2_L;
  int rem = idx / C2_L;
  int oc = rem % C2_OC;
  int b = rem / C2_OC;
  const float* ip = in + (size_t)b * C1_OC * C1_L;
  const float* wp = w + oc * C1_OC * 3;
  float bb = bias[oc];
  float s0 = bb, s1 = bb, s2 = bb;
  int tc = t * 3;
  for (int ic = 0; ic < C1_OC; ic++) {
    const float* r = ip + ic * C1_L + tc;
    float v0 = r[0], v1 = r[1], v2 = r[2], v3 = r[3], v4 = r[4];
    float w0 = wp[ic * 3], w1 = wp[ic * 3 + 1], w2 = wp[ic * 3 + 2];
    s0 = fmaf(v0, w0, fmaf(v1, w1, fmaf(v2, w2, s0)));
    s1 = fmaf(v1, w0, fmaf(v2, w1, fmaf(v3, w2, s1)));
    s2 = fmaf(v2, w0, fmaf(v3, w1, fmaf(v4, w2, s2)));
  }
  outp[idx] = fmaxf(fmaxf(s0, fmaxf(s1, s2)), 0.f);
}

__global__ void conv3_kernel(const float* __restrict__ in, const float* __restrict__ w,
                             const float* __restrict__ bias, float* __restrict__ outp) {
  int idx = blockIdx.x * 256 + threadIdx.x;
  if (idx >= NB * C3_OC * C3_L) return;
  int t = idx % C3_L;
  int rem = idx / C3_L;
  int oc = rem % C3_OC;
  int b = rem / C3_OC;
  const float* ip = in + (size_t)b * C2_OC * C2_L;
  const float* wp = w + oc * C2_OC * 3;
  float bb = bias[oc];
  float s0 = bb, s1 = bb, s2 = bb;
  int tc = t * 3;
  for (int ic = 0; ic < C2_OC; ic++) {
    const float* r = ip + ic * C2_L + tc;
    float v0 = r[0], v1 = r[1], v2 = r[2], v3 = r[3], v4 = r[4];
    float w0 = wp[ic * 3], w1 = wp[ic * 3 + 1], w2 = wp[ic * 3 + 2];
    s0 = fmaf(v0, w0, fmaf(v1, w1, fmaf(v2, w2, s0)));
    s1 = fmaf(v1, w0, fmaf(v2, w1, fmaf(v3, w2, s1)));
    s2 = fmaf(v2, w0, fmaf(v3, w1, fmaf(v4, w2, s2)));
  }
  outp[idx] = fmaxf(fmaxf(s0, fmaxf(s1, s2)), 0.f);
}

__global__ void lin1_kernel(const float* __restrict__ x, const float* __restrict__ w,
                            const float* __restrict__ bias, float* __restrict__ outp) {
  int gid = blockIdx.x * 4 + (threadIdx.x >> 6);
  int lane = threadIdx.x & 63;
  int b = gid / LIN1_OUT;
  int o = gid % LIN1_OUT;
  const float* xp = x + (size_t)b * LIN1_IN;
  const float* wp = w + (size_t)o * LIN1_IN;
  float s = 0.f;
  for (int k = lane; k < LIN1_IN; k += 64) s = fmaf(xp[k], wp[k], s);
#pragma unroll
  for (int off = 32; off > 0; off >>= 1) s += __shfl_down(s, off, 64);
  if (lane == 0) outp[b * LIN1_OUT + o] = fmaxf(s + bias[o], 0.f);
}

__global__ void lin2_kernel(const float* __restrict__ x, const float* __restrict__ w,
                            const float* __restrict__ bias, float* __restrict__ outp) {
  int tid = threadIdx.x;
  int b = tid >> 2, o = tid & 3;
  const float* xp = x + b * LIN1_OUT;
  const float* wp = w + o * LIN1_OUT;
  float s = bias[o];
  for (int k = 0; k < LIN1_OUT; k++) s = fmaf(xp[k], wp[k], s);
  outp[b * 4 + o] = fmaxf(s, 0.f);
}

// ================= launch =================
extern "C" void kernel_launch(void* const* d_in, const int* in_sizes, int n_in,
                              void* d_out, int out_size, void* d_ws, size_t ws_size,
                              hipStream_t stream) {
  const int* tokens = (const int*)d_in[0];
  const int* edge_index = (const int*)d_in[1];
  const int* batch = (const int*)d_in[2];
  const float* embed = (const float*)d_in[3];
  const float* W_ggc = (const float*)d_in[4];
  const float* W_ih = (const float*)d_in[5];
  const float* W_hh = (const float*)d_in[6];
  const float* b_ih = (const float*)d_in[7];
  const float* b_hh = (const float*)d_in[8];
  const float* c1w = (const float*)d_in[9];
  const float* c1b = (const float*)d_in[10];
  const float* c2w = (const float*)d_in[11];
  const float* c2b = (const float*)d_in[12];
  const float* c3w = (const float*)d_in[13];
  const float* c3b = (const float*)d_in[14];
  const float* l1w = (const float*)d_in[15];
  const float* l1b = (const float*)d_in[16];
  const float* l2w = (const float*)d_in[17];
  const float* l2b = (const float*)d_in[18];
  float* out = (float*)d_out;

  const int* e_src = edge_index;
  const int* e_dst = edge_index + N_EDGES;

  char* ws = (char*)d_ws;
  size_t off = 0;
  auto alloc = [&](size_t bytes) -> void* {
    void* p = ws + off;
    off = (off + bytes + 255) & ~(size_t)255;
    return p;
  };

  const size_t ACT = sizeof(_Float16) * (size_t)MP * SEG;   // 40.77 MB
  _Float16* hA = (_Float16*)alloc(ACT);
  _Float16* hB = (_Float16*)alloc(ACT);
  _Float16* m_half = (_Float16*)alloc(ACT);
  _Float16* agg_half = (_Float16*)alloc(ACT);
  _Float16* Wg_b = (_Float16*)alloc(sizeof(_Float16) * (size_t)LAYERS * NW * SEG);  // 33 MB
  _Float16* Wih_b = (_Float16*)alloc(sizeof(_Float16) * (size_t)NG * SEG);         // 24.4 MB
  _Float16* Whh_b = (_Float16*)alloc(sizeof(_Float16) * (size_t)NG * SEG);         // 24.4 MB
  int* counts = (int*)alloc(sizeof(int) * (N_NODES + 1));
  int* row_off = (int*)alloc(sizeof(int) * (N_NODES + 1));
  int* cursor = (int*)alloc(sizeof(int) * N_NODES);
  int* csr_src = (int*)alloc(sizeof(int) * N_EDGES);
  int* starts = (int*)alloc(sizeof(int) * (NB + 1));

  // tail buffers alias the (dead-by-then) m_half region: 17.6 MB < 40.77 MB
  char* tb = (char*)m_half;
  size_t toff = 0;
  auto talloc = [&](size_t bytes) -> void* {
    void* p = tb + toff;
    toff = (toff + bytes + 255) & ~(size_t)255;
    return p;
  };
  float* pooled = (float*)talloc(sizeof(float) * NB * H);
  float* c1 = (float*)talloc(sizeof(float) * (size_t)NB * C1_OC * C1_L);
  float* c2 = (float*)talloc(sizeof(float) * (size_t)NB * C2_OC * C2_L);
  float* c3 = (float*)talloc(sizeof(float) * (size_t)NB * C3_OC * C3_L);
  float* l1out = (float*)talloc(sizeof(float) * NB * LIN1_OUT);

  hipMemsetAsync(counts, 0, sizeof(int) * (N_NODES + 1), stream);
  hipMemsetAsync(cursor, 0, sizeof(int) * N_NODES, stream);

  // weight prep
  {
    dim3 g((SEG + 255) / 256, NG);
    prep_wbt16_kernel<<<g, 256, 0, stream>>>(W_ih, Wih_b);
    prep_wbt16_kernel<<<g, 256, 0, stream>>>(W_hh, Whh_b);
    dim3 gg(SEG / 32, NW / 32, LAYERS);
    prep_wg16_kernel<<<gg, 256, 0, stream>>>(W_ggc, Wg_b);
  }

  embed16_kernel<<<N_NODES, 256, 0, stream>>>(tokens, embed, hA);
  hist_kernel<<<(N_EDGES + 255) / 256, 256, 0, stream>>>(e_dst, counts, N_EDGES);
  scan_kernel<<<1, 1024, 0, stream>>>(counts, row_off, N_NODES);
  scatter_kernel<<<(N_EDGES + 255) / 256, 256, 0, stream>>>(e_src, e_dst, row_off, cursor,
                                                            csr_src, N_EDGES);
  starts_kernel<<<(N_NODES + 255) / 256, 256, 0, stream>>>(batch, starts, N_NODES);

  dim3 grid_m(NW / 128, MP / 128);      // 16 x 79
  dim3 grid_gru(SEG / 32, MP / 128);    // 63 x 79
  _Float16* hc = hA;
  _Float16* hn = hB;
  for (int l = 0; l < LAYERS; l++) {
    gemm16_kernel<<<grid_m, 256, 0, stream>>>(hc, Wg_b + (size_t)l * NW * SEG, m_half);
    agg16_kernel<<<N_NODES, 256, 0, stream>>>(m_half, row_off, csr_src, agg_half);
    gru16_kernel<<<grid_gru, 256, 0, stream>>>(agg_half, hc, Wih_b, Whh_b, b_ih, b_hh, hn);
    _Float16* t = hc; hc = hn; hn = t;
  }
  // hc == hA after 4 layers

  pool16_kernel<<<NB, 256, 0, stream>>>(hc, starts, pooled);
  conv1_kernel<<<NB, 256, 0, stream>>>(pooled, c1w, c1b, c1);
  conv2_kernel<<<(NB * C2_OC * C2_L + 255) / 256, 256, 0, stream>>>(c1, c2w, c2b, c2);
  conv3_kernel<<<(NB * C3_OC * C3_L + 255) / 256, 256, 0, stream>>>(c2, c3w, c3b, c3);
  lin1_kernel<<<NB * LIN1_OUT / 4, 256, 0, stream>>>(c3, l1w, l1b, l1out);
  lin2_kernel<<<1, 256, 0, stream>>>(l1out, l2w, l2b, out);
}

// Round 4
// 5387.853 us; speedup vs baseline: 7.0788x; 1.0210x over previous
//
#include <hip/hip_runtime.h>
#include <math.h>

#define N_NODES 10000
#define N_EDGES 100000
#define NB      64
#define EMB     100
#define H       2000
#define LAYERS  4

#define C1_OC 50
#define C1_L  666
#define C2_OC 100
#define C2_L  221
#define C3_OC 150
#define C3_L  73
#define LIN1_IN  10950
#define LIN1_OUT 500

// fp16 GEMM geometry
#define SEG  2016          // K = H padded to 32
#define MP   10112         // M = N_NODES padded to 128
#define NW   2048          // Wg output cols padded to 128
#define KK2  4032          // concat K for GRU ([Agg | Hc])
#define NPACK 8064         // 4 gates * 2016 h-cols, gate-interleaved per 16

using half8 = __attribute__((ext_vector_type(8))) _Float16;
using f32x4 = __attribute__((ext_vector_type(4))) float;

__device__ inline void gload16(const void* g, void* l) {
  __builtin_amdgcn_global_load_lds(
      (const __attribute__((address_space(1))) unsigned int*)g,
      (__attribute__((address_space(3))) unsigned int*)l, 16, 0, 0);
}

// ---------------- embedding -> fp16 h ----------------
__global__ void embed16_kernel(const int* __restrict__ tokens,
                               const float* __restrict__ table,
                               _Float16* __restrict__ h) {
  int n = blockIdx.x;
  int tok = tokens[n];
  for (int c = threadIdx.x; c < SEG; c += 256) {
    float v = (c < EMB) ? table[tok * EMB + c] : 0.f;
    h[(size_t)n * SEG + c] = (_Float16)v;
  }
}

// ---------------- CSR build ----------------
__global__ void hist_kernel(const int* __restrict__ dst, int* __restrict__ counts, int e) {
  int i = blockIdx.x * 256 + threadIdx.x;
  if (i < e) atomicAdd(&counts[dst[i]], 1);
}

__global__ void scan_kernel(const int* __restrict__ counts, int* __restrict__ row_off, int n) {
  __shared__ int sums[1024];
  int tid = threadIdx.x;
  const int CH = (n + 1023) / 1024;
  int start = tid * CH;
  int local = 0;
  for (int i = 0; i < CH; i++)
    if (start + i < n) local += counts[start + i];
  sums[tid] = local;
  __syncthreads();
  for (int off = 1; off < 1024; off <<= 1) {
    int v = (tid >= off) ? sums[tid - off] : 0;
    __syncthreads();
    sums[tid] += v;
    __syncthreads();
  }
  int run = (tid > 0) ? sums[tid - 1] : 0;
  for (int i = 0; i < CH; i++)
    if (start + i < n) { row_off[start + i] = run; run += counts[start + i]; }
  if (tid == 1023) row_off[n] = run;
}

__global__ void scatter_kernel(const int* __restrict__ src, const int* __restrict__ dst,
                               const int* __restrict__ row_off, int* __restrict__ cursor,
                               int* __restrict__ csr_src, int e) {
  int i = blockIdx.x * 256 + threadIdx.x;
  if (i < e) {
    int d = dst[i];
    int pos = atomicAdd(&cursor[d], 1);
    csr_src[row_off[d] + pos] = src[i];
  }
}

__global__ void starts_kernel(const int* __restrict__ batch, int* __restrict__ starts, int n) {
  int i = blockIdx.x * 256 + threadIdx.x;
  if (i >= n) return;
  int b = batch[i];
  int pb = (i == 0) ? -1 : batch[i - 1];
  if (b != pb)
    for (int x = pb + 1; x <= b; x++) starts[x] = i;
  if (i == n - 1)
    for (int x = b + 1; x <= NB; x++) starts[x] = n;
}

// ---------------- weight prep ----------------
// W_ggc[l] (H x H) -> transposed fp16 Bt: out[l][n][k] = W[k][n], n<NW, k<SEG
__global__ void prep_wg16_kernel(const float* __restrict__ Wg, _Float16* __restrict__ out) {
  __shared__ float t[32][33];
  int l = blockIdx.z;
  const float* W = Wg + (size_t)l * H * H;
  _Float16* o = out + (size_t)l * NW * SEG;
  int kt = blockIdx.x * 32, nt = blockIdx.y * 32;
  int tx = threadIdx.x & 31, ty = threadIdx.x >> 5;  // ty 0..7
#pragma unroll
  for (int i = 0; i < 4; i++) {
    int k = kt + ty + i * 8, n = nt + tx;
    t[tx][ty + i * 8] = (k < H && n < H) ? W[(size_t)k * H + n] : 0.f;
  }
  __syncthreads();
#pragma unroll
  for (int i = 0; i < 4; i++) {
    int nl = ty + i * 8, kl = tx;
    o[(size_t)(nt + nl) * SEG + (kt + kl)] = (_Float16)t[nl][kl];
  }
}

// Packed GRU weight matrix Wp: NPACK rows x KK2 cols.
// row n: gate=(n>>4)&3, hcol=(n>>6)*16+(n&15)
// gate0 (r): [Wih_r | Whh_r]; gate1 (z): [Wih_z | Whh_z]
// gate2 (inn): [Wih_n | 0];   gate3 (hn): [0 | Whh_n]
__global__ void prep_wpack_kernel(const float* __restrict__ Wih, const float* __restrict__ Whh,
                                  _Float16* __restrict__ out) {
  int n = blockIdx.y;
  int k = blockIdx.x * 256 + threadIdx.x;
  if (k >= KK2) return;
  int gate = (n >> 4) & 3;
  int hcol = ((n >> 6) << 4) + (n & 15);
  float v = 0.f;
  if (hcol < H) {
    if (gate < 2) {
      int row = gate * H + hcol;
      if (k < 2016) { if (k < H) v = Wih[(size_t)row * H + k]; }
      else { int k2 = k - 2016; if (k2 < H) v = Whh[(size_t)row * H + k2]; }
    } else if (gate == 2) {
      if (k < H) v = Wih[(size_t)(2 * H + hcol) * H + k];
    } else {
      int k2 = k - 2016;
      if (k2 >= 0 && k2 < H) v = Whh[(size_t)(2 * H + hcol) * H + k2];
    }
  }
  out[(size_t)n * KK2 + k] = (_Float16)v;
}

// ---------------- fp16 GEMM: C[m][n] = sum_k A[m][k] * Bt[n][k], fp16 out ----------------
__global__ __launch_bounds__(256) void gemm16_kernel(
    const _Float16* __restrict__ A, const _Float16* __restrict__ Bt,
    _Float16* __restrict__ C) {
  __shared__ __align__(16) _Float16 As[128][32];
  __shared__ __align__(16) _Float16 Bs[128][32];
  const int tid = threadIdx.x;
  const int wave = tid >> 6, lane = tid & 63;
  const int bm = blockIdx.y * 128, bn = blockIdx.x * 128;
  const int wm = (wave & 1) * 64, wn = (wave >> 1) * 64;
  const int srow = lane >> 2, scol = (lane & 3) * 8;
  const int fr = lane & 15, quad = lane >> 4;

  f32x4 acc[4][4];
#pragma unroll
  for (int i = 0; i < 4; i++)
#pragma unroll
    for (int j = 0; j < 4; j++) {
      f32x4 z = {0.f, 0.f, 0.f, 0.f};
      acc[i][j] = z;
    }

  for (int k0 = 0; k0 < SEG; k0 += 32) {
    gload16(A + (size_t)(bm + wave * 32 + srow) * SEG + k0 + scol, &As[wave * 32][0]);
    gload16(A + (size_t)(bm + wave * 32 + 16 + srow) * SEG + k0 + scol, &As[wave * 32 + 16][0]);
    gload16(Bt + (size_t)(bn + wave * 32 + srow) * SEG + k0 + scol, &Bs[wave * 32][0]);
    gload16(Bt + (size_t)(bn + wave * 32 + 16 + srow) * SEG + k0 + scol, &Bs[wave * 32 + 16][0]);
    __syncthreads();
    half8 af[4], bf[4];
#pragma unroll
    for (int i = 0; i < 4; i++) {
      af[i] = *(const half8*)&As[wm + i * 16 + fr][quad * 8];
      bf[i] = *(const half8*)&Bs[wn + i * 16 + fr][quad * 8];
    }
#pragma unroll
    for (int i = 0; i < 4; i++)
#pragma unroll
      for (int j = 0; j < 4; j++)
        acc[i][j] = __builtin_amdgcn_mfma_f32_16x16x32_f16(af[i], bf[j], acc[i][j], 0, 0, 0);
    __syncthreads();
  }
#pragma unroll
  for (int i = 0; i < 4; i++)
#pragma unroll
    for (int j = 0; j < 4; j++) {
      int n = bn + wn + j * 16 + fr;
      if (n >= SEG) continue;
#pragma unroll
      for (int r = 0; r < 4; r++) {
        int m = bm + wm + i * 16 + quad * 4 + r;
        C[(size_t)m * SEG + n] = (_Float16)acc[i][j][r];
      }
    }
}

// ---------------- edge aggregation on fp16 m, fp32 accumulate, fp16 out ----------------
__global__ void agg16_kernel(const _Float16* __restrict__ m, const int* __restrict__ row_off,
                             const int* __restrict__ csr_src, _Float16* __restrict__ agg) {
  int node = blockIdx.x;
  int s = row_off[node], e = row_off[node + 1];
  int tid = threadIdx.x;
  bool act = tid < (SEG / 8);   // 252
  float a[8] = {0, 0, 0, 0, 0, 0, 0, 0};
  __shared__ int s_src[256];
  for (int base = s; base < e; base += 256) {
    int cnt = min(256, e - base);
    __syncthreads();
    if (tid < cnt) s_src[tid] = csr_src[base + tid];
    __syncthreads();
    for (int p = 0; p < cnt; p++) {
      if (act) {
        half8 v = *(const half8*)&m[(size_t)s_src[p] * SEG + tid * 8];
#pragma unroll
        for (int i = 0; i < 8; i++) a[i] += (float)v[i];
      }
    }
  }
  if (act) {
    half8 o;
#pragma unroll
    for (int i = 0; i < 8; i++) o[i] = (_Float16)a[i];
    *(half8*)&agg[(size_t)node * SEG + tid * 8] = o;
  }
}

// ---------------- fused GRU: concat-K GEMM, gate-interleaved N, local epilogue ----------------
// A-virtual = [Agg | Hc] (M x 4032); B = Wp (NPACK x 4032).
// Wave's 4 j-tiles = gates r,z,inn,hn of the same 16 h-cols -> lane-local GRU blend.
__global__ __launch_bounds__(256) void gru16b_kernel(
    const _Float16* __restrict__ Agg, const _Float16* __restrict__ Hc,
    const _Float16* __restrict__ Wp,
    const float* __restrict__ b_ih, const float* __restrict__ b_hh,
    _Float16* __restrict__ Hn) {
  __shared__ __align__(16) _Float16 As[128][32];
  __shared__ __align__(16) _Float16 Bs[128][32];
  const int tid = threadIdx.x;
  const int wave = tid >> 6, lane = tid & 63;
  const int bm = blockIdx.y * 128, bn = blockIdx.x * 128;
  const int wm = (wave & 1) * 64, wn = (wave >> 1) * 64;
  const int srow = lane >> 2, scol = (lane & 3) * 8;
  const int fr = lane & 15, quad = lane >> 4;
  const int c = blockIdx.x * 32 + (wave >> 1) * 16 + fr;   // h-col for this lane

  f32x4 acc[4][4];   // [row-tile][gate]
#pragma unroll
  for (int i = 0; i < 4; i++)
#pragma unroll
    for (int j = 0; j < 4; j++) {
      f32x4 z = {0.f, 0.f, 0.f, 0.f};
      acc[i][j] = z;
    }

  for (int k0 = 0; k0 < KK2; k0 += 32) {
    const bool first = (k0 < 2016);
    const int kk = first ? k0 : (k0 - 2016);
    const _Float16* Ab = first ? Agg : Hc;
    gload16(Ab + (size_t)(bm + wave * 32 + srow) * SEG + kk + scol, &As[wave * 32][0]);
    gload16(Ab + (size_t)(bm + wave * 32 + 16 + srow) * SEG + kk + scol, &As[wave * 32 + 16][0]);
    gload16(Wp + (size_t)(bn + wave * 32 + srow) * KK2 + k0 + scol, &Bs[wave * 32][0]);
    gload16(Wp + (size_t)(bn + wave * 32 + 16 + srow) * KK2 + k0 + scol, &Bs[wave * 32 + 16][0]);
    __syncthreads();
    half8 af[4];
#pragma unroll
    for (int i = 0; i < 4; i++)
      af[i] = *(const half8*)&As[wm + i * 16 + fr][quad * 8];
    half8 bf0 = *(const half8*)&Bs[wn + 0 * 16 + fr][quad * 8];
    half8 bf1 = *(const half8*)&Bs[wn + 1 * 16 + fr][quad * 8];
    int jn = first ? 2 : 3;
    half8 bfn = *(const half8*)&Bs[wn + jn * 16 + fr][quad * 8];
#pragma unroll
    for (int i = 0; i < 4; i++) {
      acc[i][0] = __builtin_amdgcn_mfma_f32_16x16x32_f16(af[i], bf0, acc[i][0], 0, 0, 0);
      acc[i][1] = __builtin_amdgcn_mfma_f32_16x16x32_f16(af[i], bf1, acc[i][1], 0, 0, 0);
    }
    if (first) {
#pragma unroll
      for (int i = 0; i < 4; i++)
        acc[i][2] = __builtin_amdgcn_mfma_f32_16x16x32_f16(af[i], bfn, acc[i][2], 0, 0, 0);
    } else {
#pragma unroll
      for (int i = 0; i < 4; i++)
        acc[i][3] = __builtin_amdgcn_mfma_f32_16x16x32_f16(af[i], bfn, acc[i][3], 0, 0, 0);
    }
    __syncthreads();
  }

  if (c >= H) return;
  const float b_r = b_ih[c] + b_hh[c];
  const float b_z = b_ih[H + c] + b_hh[H + c];
  const float b_in = b_ih[2 * H + c];
  const float b_hn = b_hh[2 * H + c];
#pragma unroll
  for (int i = 0; i < 4; i++) {
#pragma unroll
    for (int r = 0; r < 4; r++) {
      int m = bm + wm + i * 16 + quad * 4 + r;
      float rg = 1.f / (1.f + expf(-(acc[i][0][r] + b_r)));
      float zg = 1.f / (1.f + expf(-(acc[i][1][r] + b_z)));
      float nn = tanhf(acc[i][2][r] + b_in + rg * (acc[i][3][r] + b_hn));
      float hold = (float)Hc[(size_t)m * SEG + c];
      Hn[(size_t)m * SEG + c] = (_Float16)((1.f - zg) * nn + zg * hold);
    }
  }
}

// ---------------- relu + segment max pool (fp16 in, fp32 out) ----------------
__global__ void pool16_kernel(const _Float16* __restrict__ h, const int* __restrict__ starts,
                              float* __restrict__ pooled) {
  int b = blockIdx.x;
  int s = starts[b], e = starts[b + 1];
  for (int idx = threadIdx.x; idx < H; idx += 256) {
    float mx = 0.f;  // relu floor
    for (int n = s; n < e; n++) mx = fmaxf(mx, (float)h[(size_t)n * SEG + idx]);
    pooled[b * H + idx] = mx;
  }
}

// ---------------- conv / linear tail (fp32) ----------------
__global__ void conv1_kernel(const float* __restrict__ in, const float* __restrict__ w,
                             const float* __restrict__ bias, float* __restrict__ outp) {
  __shared__ float sin_[H];
  int b = blockIdx.x;
  for (int j = threadIdx.x; j < H; j += 256) sin_[j] = in[(size_t)b * H + j];
  __syncthreads();
  for (int idx = threadIdx.x; idx < C1_OC * C1_L; idx += 256) {
    int oc = idx / C1_L, t = idx % C1_L;
    float w0 = w[oc * 3], w1 = w[oc * 3 + 1], w2 = w[oc * 3 + 2];
    float bb = bias[oc];
    float best = 0.f;
    int base = t * 3;
#pragma unroll
    for (int p = 0; p < 3; p++) {
      float v = fmaf(sin_[base + p], w0, fmaf(sin_[base + p + 1], w1,
                fmaf(sin_[base + p + 2], w2, bb)));
      best = fmaxf(best, v);
    }
    outp[((size_t)b * C1_OC + oc) * C1_L + t] = best;
  }
}

__global__ void conv2_kernel(const float* __restrict__ in, const float* __restrict__ w,
                             const float* __restrict__ bias, float* __restrict__ outp) {
  int idx = blockIdx.x * 256 + threadIdx.x;
  if (idx >= NB * C2_OC * C2_L) return;
  int t = idx % C2_L;
  int rem = idx / C2_L;
  int oc = rem % C2_OC;
  int b = rem / C2_OC;
  const float* ip = in + (size_t)b * C1_OC * C1_L;
  const float* wp = w + oc * C1_OC * 3;
  float bb = bias[oc];
  float s0 = bb, s1 = bb, s2 = bb;
  int tc = t * 3;
  for (int ic = 0; ic < C1_OC; ic++) {
    const float* r = ip + ic * C1_L + tc;
    float v0 = r[0], v1 = r[1], v2 = r[2], v3 = r[3], v4 = r[4];
    float w0 = wp[ic * 3], w1 = wp[ic * 3 + 1], w2 = wp[ic * 3 + 2];
    s0 = fmaf(v0, w0, fmaf(v1, w1, fmaf(v2, w2, s0)));
    s1 = fmaf(v1, w0, fmaf(v2, w1, fmaf(v3, w2, s1)));
    s2 = fmaf(v2, w0, fmaf(v3, w1, fmaf(v4, w2, s2)));
  }
  outp[idx] = fmaxf(fmaxf(s0, fmaxf(s1, s2)), 0.f);
}

__global__ void conv3_kernel(const float* __restrict__ in, const float* __restrict__ w,
                             const float* __restrict__ bias, float* __restrict__ outp) {
  int idx = blockIdx.x * 256 + threadIdx.x;
  if (idx >= NB * C3_OC * C3_L) return;
  int t = idx % C3_L;
  int rem = idx / C3_L;
  int oc = rem % C3_OC;
  int b = rem / C3_OC;
  const float* ip = in + (size_t)b * C2_OC * C2_L;
  const float* wp = w + oc * C2_OC * 3;
  float bb = bias[oc];
  float s0 = bb, s1 = bb, s2 = bb;
  int tc = t * 3;
  for (int ic = 0; ic < C2_OC; ic++) {
    const float* r = ip + ic * C2_L + tc;
    float v0 = r[0], v1 = r[1], v2 = r[2], v3 = r[3], v4 = r[4];
    float w0 = wp[ic * 3], w1 = wp[ic * 3 + 1], w2 = wp[ic * 3 + 2];
    s0 = fmaf(v0, w0, fmaf(v1, w1, fmaf(v2, w2, s0)));
    s1 = fmaf(v1, w0, fmaf(v2, w1, fmaf(v3, w2, s1)));
    s2 = fmaf(v2, w0, fmaf(v3, w1, fmaf(v4, w2, s2)));
  }
  outp[idx] = fmaxf(fmaxf(s0, fmaxf(s1, s2)), 0.f);
}

__global__ void lin1_kernel(const float* __restrict__ x, const float* __restrict__ w,
                            const float* __restrict__ bias, float* __restrict__ outp) {
  int gid = blockIdx.x * 4 + (threadIdx.x >> 6);
  int lane = threadIdx.x & 63;
  int b = gid / LIN1_OUT;
  int o = gid % LIN1_OUT;
  const float* xp = x + (size_t)b * LIN1_IN;
  const float* wp = w + (size_t)o * LIN1_IN;
  float s = 0.f;
  for (int k = lane; k < LIN1_IN; k += 64) s = fmaf(xp[k], wp[k], s);
#pragma unroll
  for (int off = 32; off > 0; off >>= 1) s += __shfl_down(s, off, 64);
  if (lane == 0) outp[b * LIN1_OUT + o] = fmaxf(s + bias[o], 0.f);
}

__global__ void lin2_kernel(const float* __restrict__ x, const float* __restrict__ w,
                            const float* __restrict__ bias, float* __restrict__ outp) {
  int tid = threadIdx.x;
  int b = tid >> 2, o = tid & 3;
  const float* xp = x + b * LIN1_OUT;
  const float* wp = w + o * LIN1_OUT;
  float s = bias[o];
  for (int k = 0; k < LIN1_OUT; k++) s = fmaf(xp[k], wp[k], s);
  outp[b * 4 + o] = fmaxf(s, 0.f);
}

// ================= launch =================
extern "C" void kernel_launch(void* const* d_in, const int* in_sizes, int n_in,
                              void* d_out, int out_size, void* d_ws, size_t ws_size,
                              hipStream_t stream) {
  const int* tokens = (const int*)d_in[0];
  const int* edge_index = (const int*)d_in[1];
  const int* batch = (const int*)d_in[2];
  const float* embed = (const float*)d_in[3];
  const float* W_ggc = (const float*)d_in[4];
  const float* W_ih = (const float*)d_in[5];
  const float* W_hh = (const float*)d_in[6];
  const float* b_ih = (const float*)d_in[7];
  const float* b_hh = (const float*)d_in[8];
  const float* c1w = (const float*)d_in[9];
  const float* c1b = (const float*)d_in[10];
  const float* c2w = (const float*)d_in[11];
  const float* c2b = (const float*)d_in[12];
  const float* c3w = (const float*)d_in[13];
  const float* c3b = (const float*)d_in[14];
  const float* l1w = (const float*)d_in[15];
  const float* l1b = (const float*)d_in[16];
  const float* l2w = (const float*)d_in[17];
  const float* l2b = (const float*)d_in[18];
  float* out = (float*)d_out;

  const int* e_src = edge_index;
  const int* e_dst = edge_index + N_EDGES;

  char* ws = (char*)d_ws;
  size_t off = 0;
  auto alloc = [&](size_t bytes) -> void* {
    void* p = ws + off;
    off = (off + bytes + 255) & ~(size_t)255;
    return p;
  };

  const size_t ACT = sizeof(_Float16) * (size_t)MP * SEG;   // 40.77 MB
  _Float16* bufX = (_Float16*)alloc(ACT);                   // h (current)
  _Float16* bufY = (_Float16*)alloc(ACT);                   // m / h_next (rotates with X)
  _Float16* bufZ = (_Float16*)alloc(ACT);                   // agg (fixed)
  _Float16* Wg_b = (_Float16*)alloc(sizeof(_Float16) * (size_t)LAYERS * NW * SEG);  // 33 MB
  _Float16* Wp   = (_Float16*)alloc(sizeof(_Float16) * (size_t)NPACK * KK2);        // 65 MB
  int* counts = (int*)alloc(sizeof(int) * (N_NODES + 1));
  int* row_off = (int*)alloc(sizeof(int) * (N_NODES + 1));
  int* cursor = (int*)alloc(sizeof(int) * N_NODES);
  int* csr_src = (int*)alloc(sizeof(int) * N_EDGES);
  int* starts = (int*)alloc(sizeof(int) * (NB + 1));

  // tail buffers alias bufZ (agg dead after last gru): 17.6 MB < 40.77 MB
  char* tb = (char*)bufZ;
  size_t toff = 0;
  auto talloc = [&](size_t bytes) -> void* {
    void* p = tb + toff;
    toff = (toff + bytes + 255) & ~(size_t)255;
    return p;
  };
  float* pooled = (float*)talloc(sizeof(float) * NB * H);
  float* c1 = (float*)talloc(sizeof(float) * (size_t)NB * C1_OC * C1_L);
  float* c2 = (float*)talloc(sizeof(float) * (size_t)NB * C2_OC * C2_L);
  float* c3 = (float*)talloc(sizeof(float) * (size_t)NB * C3_OC * C3_L);
  float* l1out = (float*)talloc(sizeof(float) * NB * LIN1_OUT);

  hipMemsetAsync(counts, 0, sizeof(int) * (N_NODES + 1), stream);
  hipMemsetAsync(cursor, 0, sizeof(int) * N_NODES, stream);

  // weight prep
  {
    dim3 gg(SEG / 32, NW / 32, LAYERS);
    prep_wg16_kernel<<<gg, 256, 0, stream>>>(W_ggc, Wg_b);
    dim3 gp((KK2 + 255) / 256, NPACK);
    prep_wpack_kernel<<<gp, 256, 0, stream>>>(W_ih, W_hh, Wp);
  }

  embed16_kernel<<<N_NODES, 256, 0, stream>>>(tokens, embed, bufX);
  hist_kernel<<<(N_EDGES + 255) / 256, 256, 0, stream>>>(e_dst, counts, N_EDGES);
  scan_kernel<<<1, 1024, 0, stream>>>(counts, row_off, N_NODES);
  scatter_kernel<<<(N_EDGES + 255) / 256, 256, 0, stream>>>(e_src, e_dst, row_off, cursor,
                                                            csr_src, N_EDGES);
  starts_kernel<<<(N_NODES + 255) / 256, 256, 0, stream>>>(batch, starts, N_NODES);

  dim3 grid_m(NW / 128, MP / 128);        // 16 x 79
  dim3 grid_gru(NPACK / 128, MP / 128);   // 63 x 79
  _Float16* X = bufX;
  _Float16* Y = bufY;
  for (int l = 0; l < LAYERS; l++) {
    gemm16_kernel<<<grid_m, 256, 0, stream>>>(X, Wg_b + (size_t)l * NW * SEG, Y);
    agg16_kernel<<<N_NODES, 256, 0, stream>>>(Y, row_off, csr_src, bufZ);
    gru16b_kernel<<<grid_gru, 256, 0, stream>>>(bufZ, X, Wp, b_ih, b_hh, Y);
    _Float16* t = X; X = Y; Y = t;
  }
  // X holds final h

  pool16_kernel<<<NB, 256, 0, stream>>>(X, starts, pooled);
  conv1_kernel<<<NB, 256, 0, stream>>>(pooled, c1w, c1b, c1);
  conv2_kernel<<<(NB * C2_OC * C2_L + 255) / 256, 256, 0, stream>>>(c1, c2w, c2b, c2);
  conv3_kernel<<<(NB * C3_OC * C3_L + 255) / 256, 256, 0, stream>>>(c2, c3w, c3b, c3);
  lin1_kernel<<<NB * LIN1_OUT / 4, 256, 0, stream>>>(c3, l1w, l1b, l1out);
  lin2_kernel<<<1, 256, 0, stream>>>(l1out, l2w, l2b, out);
}